// Round 9
// baseline (133.279 us; speedup 1.0000x reference)
//
#include <hip/hip_runtime.h>
#include <hip/hip_bf16.h>

typedef __attribute__((ext_vector_type(8))) short bf16x8;
typedef __attribute__((ext_vector_type(4))) float f32x4;

#define NB 16
#define CD 256
#define HD 64
#define WD 64
#define WP 68   // padded width
#define SD 4096
#define KU 1280  // 5 * 256

__device__ __forceinline__ void gload16(const void* g, void* lds) {
  __builtin_amdgcn_global_load_lds(
      (const __attribute__((address_space(1))) unsigned int*)g,
      (__attribute__((address_space(3))) unsigned int*)lds, 16, 0, 0);
}

// ---------------- prep W3: A[o][j*256+c] = p3[o,c,0,j] (bf16) ----------------
__global__ __launch_bounds__(256) void prep_w3(const float* __restrict__ p3,
                                               __hip_bfloat16* __restrict__ A) {
  int id = blockIdx.x * 256 + threadIdx.x;
  if (id >= CD * KU) return;
  int o = id / KU;
  int r = id - o * KU;
  int j = r >> 8;
  int c = r & 255;
  A[id] = __float2bfloat16(p3[(o * CD + c) * 5 + j]);
}

// ---------------- prep X: t2p [N][H][WP][C] (zero-padded), t5T [N][S][C], t6 [N][C][S] ---
__global__ __launch_bounds__(256) void prep_x(const float* __restrict__ x,
                                              const float* __restrict__ p2,
                                              const float* __restrict__ p4,
                                              const float* __restrict__ p6,
                                              __hip_bfloat16* __restrict__ t2p,
                                              __hip_bfloat16* __restrict__ t5T,
                                              __hip_bfloat16* __restrict__ t6) {
  int h = blockIdx.x;
  int c0 = blockIdx.y * 64;
  int n = blockIdx.z;
  __shared__ float xl[64][67];
  __shared__ float p2l[64];
  __shared__ float wtl[64][8];
  int t = threadIdx.x;

  if (t < 64) p2l[t] = p2[(c0 + t) * HD + h];
  for (int idx = t; idx < 448; idx += 256) {
    int c = idx / 7, k = idx - c * 7;
    wtl[c][k] = p4[(c0 + c) * 7 + k] * p6[k];
  }

  {
    int cq = t >> 4;
    int w4 = (t & 15) * 4;
#pragma unroll
    for (int cc = 0; cc < 4; ++cc) {
      int cl = cc * 16 + cq;
      const float4 xv = *reinterpret_cast<const float4*>(
          &x[(((size_t)n * CD + c0 + cl) * HD + h) * WD + w4]);
      xl[cl][w4 + 0] = xv.x;
      xl[cl][w4 + 1] = xv.y;
      xl[cl][w4 + 2] = xv.z;
      xl[cl][w4 + 3] = xv.w;
    }
  }
  __syncthreads();

  __hip_bfloat16* t2pn = t2p + (size_t)n * HD * WP * CD;
#pragma unroll
  for (int ii = 0; ii < 2; ++ii) {
    int w = (t >> 3) + ii * 32;
    int cb = (t & 7) * 8;
    __hip_bfloat16 o2[8], o5[8];
#pragma unroll
    for (int j = 0; j < 8; ++j) {
      float xv = xl[cb + j][w];
      o5[j] = __float2bfloat16(fmaxf(xv, 0.f));
      o2[j] = __float2bfloat16(p2l[cb + j] * xv);
    }
    size_t s = (size_t)h * 64 + w;
    *reinterpret_cast<bf16x8*>(&t5T[((size_t)n * SD + s) * CD + c0 + cb]) =
        *reinterpret_cast<const bf16x8*>(o5);
    *reinterpret_cast<bf16x8*>(&t2pn[((size_t)h * WP + w + 2) * CD + c0 + cb]) =
        *reinterpret_cast<const bf16x8*>(o2);
  }
  if (t < 32) {
    int pi = t >> 3;
    int wp = (pi < 2) ? pi : pi + 64;
    int cb = (t & 7) * 8;
    bf16x8 z = (bf16x8){0, 0, 0, 0, 0, 0, 0, 0};
    *reinterpret_cast<bf16x8*>(&t2pn[((size_t)h * WP + wp) * CD + c0 + cb]) = z;
  }

#pragma unroll
  for (int ii = 0; ii < 2; ++ii) {
    int cl = (t >> 3) + ii * 32;
    int w8 = (t & 7) * 8;
    float hx[14];
#pragma unroll
    for (int m = 0; m < 14; ++m) {
      int wi = w8 - 3 + m;
      hx[m] = (wi >= 0 && wi < 64) ? xl[cl][wi] : 0.f;
    }
    float wt[7];
#pragma unroll
    for (int k = 0; k < 7; ++k) wt[k] = wtl[cl][k];
    __hip_bfloat16 o6[8];
#pragma unroll
    for (int u = 0; u < 8; ++u) {
      float acc = 0.f;
#pragma unroll
      for (int k = 0; k < 7; ++k) acc += wt[k] * hx[u + k];
      o6[u] = __float2bfloat16(acc);
    }
    *reinterpret_cast<bf16x8*>(&t6[((size_t)n * CD + c0 + cl) * SD + h * 64 + w8]) =
        *reinterpret_cast<const bf16x8*>(o6);
  }
}

// ---------------- GEMM B (4-phase/tile, 256x256 tile, BK=64, hoisted ds_reads) -------
// grid: (sb=16, 1, n=16) = 256 blocks, 512 threads (8 waves 2Mx4N, wave tile 128x64)
// LDS: 2 dbuf x (A 256x64 + B 256x64) bf16 = 128 KiB.
// Swizzle: physical 16B-granule = logical_granule ^ (row&7)  (both sides, rule 21).
// Round-8 schedule: fragments loaded a phase ahead (read latency overlaps barrier);
// B-fragments loaded ONCE per tile, reused across MH halves (24 ds_read/tile).
// ph0: MFMA(av0,bvA); ld av1,bvB; STAGE_B x4; BAR
// ph1: MFMA(av0,bvB); STAGE_A x4; BAR
// ph2: MFMA(av1,bvA); BAR
// ph3: MFMA(av1,bvB); VMWAIT(0); BAR; preload next av0,bvA
// Hazards: buf[nxt] old contents last read at kt-1 ph0 (4 barriers earlier);
// buf[cur] validated at kt-1 ph3 VMWAIT(0)+BAR; preloads issued after it.
#define STAGE_A(c, kt, d)                                                              \
  gload16(Ab + (size_t)((c) * 64 + wv * 8 + (lane >> 3)) * 2560 + (kt) * 128 + cbsrc,  \
          (char*)lds + (d) * 65536 + (c) * 8192 + wv * 1024)
#define STAGE_B(j, kt, d)                                                              \
  gload16(t2pb + (size_t)(s0 + (j) * 64 + wv * 8 + (lane >> 3) + 4 * (sb * 4 + (j))) * 512 + \
                     (kt) * 128 + cbsrc,                                               \
          (char*)lds + (d) * 65536 + 32768 + (j) * 8192 + wv * 1024)

#define LDAV(d, MH, AV)                                                                \
  do {                                                                                 \
    const __hip_bfloat16* pA =                                                         \
        lds + (d) * 32768 + (wm * 128 + (MH) * 64 + l16) * 64;                         \
    _Pragma("unroll") for (int ks = 0; ks < 2; ++ks) {                                 \
      int cb = (ks * 32 + lg * 8) ^ lxor;                                              \
      _Pragma("unroll") for (int mf = 0; mf < 4; ++mf)                                 \
          AV[ks * 4 + mf] = *reinterpret_cast<const bf16x8*>(pA + mf * 1024 + cb);     \
    }                                                                                  \
  } while (0)

#define LDBV(d, NH, BV)                                                                \
  do {                                                                                 \
    const __hip_bfloat16* pB =                                                         \
        lds + (d) * 32768 + 16384 + (wn * 64 + (NH) * 32 + l16) * 64;                  \
    _Pragma("unroll") for (int ks = 0; ks < 2; ++ks) {                                 \
      int cb = (ks * 32 + lg * 8) ^ lxor;                                              \
      _Pragma("unroll") for (int nf = 0; nf < 2; ++nf)                                 \
          BV[ks * 2 + nf] = *reinterpret_cast<const bf16x8*>(pB + nf * 1024 + cb);     \
    }                                                                                  \
  } while (0)

#define MFMAQ(MH, NH, AV, BV)                                                          \
  do {                                                                                 \
    __builtin_amdgcn_s_setprio(1);                                                     \
    _Pragma("unroll") for (int ks = 0; ks < 2; ++ks)                                   \
        _Pragma("unroll") for (int mf = 0; mf < 4; ++mf)                               \
            _Pragma("unroll") for (int nf = 0; nf < 2; ++nf)                           \
                acc[(MH) * 4 + mf][(NH) * 2 + nf] = __builtin_amdgcn_mfma_f32_16x16x32_bf16( \
                    AV[ks * 4 + mf], BV[ks * 2 + nf], acc[(MH) * 4 + mf][(NH) * 2 + nf], \
                    0, 0, 0);                                                          \
    __builtin_amdgcn_s_setprio(0);                                                     \
  } while (0)

#define VMWAIT(N) asm volatile("s_waitcnt vmcnt(" #N ")" ::: "memory")
#define BARRIER() __builtin_amdgcn_s_barrier()

__global__ __launch_bounds__(512, 2) void gemm_b8(const __hip_bfloat16* __restrict__ A,
                                                  const __hip_bfloat16* __restrict__ t2p,
                                                  __hip_bfloat16* __restrict__ t3) {
  __shared__ __align__(16) __hip_bfloat16 lds[65536];  // 128 KiB
  const int n = blockIdx.z;
  const int sb = blockIdx.x;
  const int t = threadIdx.x;
  const int wv = t >> 6, lane = t & 63;
  const int wm = wv >> 2, wn = wv & 3;
  const int l16 = lane & 15, lg = lane >> 4;
  const int s0 = sb * 256;
  const char* Ab = (const char*)A;
  const char* t2pb = (const char*)(t2p + (size_t)n * HD * WP * CD);
  const int cbsrc = ((lane & 7) ^ (lane >> 3)) * 16;  // src-side swizzle (granule)
  const int lxor = (l16 & 7) * 8;                     // read-side row XOR (elems)

  f32x4 acc[8][4];
#pragma unroll
  for (int i = 0; i < 8; ++i)
#pragma unroll
    for (int j = 0; j < 4; ++j) acc[i][j] = (f32x4){0.f, 0.f, 0.f, 0.f};

  bf16x8 av0[8], av1[8], bvA[4], bvB[4];

  // prologue: stage kt=0 into buf 0, validate, preload first fragments
  STAGE_B(0, 0, 0); STAGE_B(1, 0, 0); STAGE_B(2, 0, 0); STAGE_B(3, 0, 0);
  STAGE_A(0, 0, 0); STAGE_A(1, 0, 0); STAGE_A(2, 0, 0); STAGE_A(3, 0, 0);
  VMWAIT(0);
  BARRIER();
  LDAV(0, 0, av0);
  LDBV(0, 0, bvA);

  for (int kt = 0; kt < 19; ++kt) {
    const int cur = kt & 1, nxt = cur ^ 1, kn = kt + 1;
    // ph0: quadrant (0,0); prefetch av1/bvB; stage B of kt+1
    LDAV(cur, 1, av1);
    LDBV(cur, 1, bvB);
    MFMAQ(0, 0, av0, bvA);
    STAGE_B(0, kn, nxt); STAGE_B(1, kn, nxt); STAGE_B(2, kn, nxt); STAGE_B(3, kn, nxt);
    BARRIER();
    // ph1: (0,1); stage A of kt+1
    MFMAQ(0, 1, av0, bvB);
    STAGE_A(0, kn, nxt); STAGE_A(1, kn, nxt); STAGE_A(2, kn, nxt); STAGE_A(3, kn, nxt);
    BARRIER();
    // ph2: (1,0) — bvA reused (B-fragments are MH-independent)
    MFMAQ(1, 0, av1, bvA);
    BARRIER();
    // ph3: (1,1); drain kt+1's loads; preload next tile's av0/bvA
    MFMAQ(1, 1, av1, bvB);
    VMWAIT(0);
    BARRIER();
    LDAV(nxt, 0, av0);
    LDBV(nxt, 0, bvA);
  }
  // peeled last tile kt=19 (buf 1): av0/bvA preloaded; no staging, no barriers
  LDAV(1, 1, av1);
  LDBV(1, 1, bvB);
  MFMAQ(0, 0, av0, bvA);
  MFMAQ(0, 1, av0, bvB);
  MFMAQ(1, 0, av1, bvA);
  MFMAQ(1, 1, av1, bvB);

  __hip_bfloat16* t3n = t3 + (size_t)n * CD * SD;
#pragma unroll
  for (int im = 0; im < 8; ++im)
#pragma unroll
    for (int in = 0; in < 4; ++in) {
      int row0 = wm * 128 + im * 16 + lg * 4;
      int col = s0 + wn * 64 + in * 16 + l16;
#pragma unroll
      for (int r = 0; r < 4; ++r)
        t3n[(size_t)(row0 + r) * SD + col] = __float2bfloat16(acc[im][in][r]);
    }
}

// ---------------- GEMM C (K-split x4): P4[kc][n][d][c] = sum_{s in chunk} t6*t3 ---------
__global__ __launch_bounds__(256) void gemm_c_part(const __hip_bfloat16* __restrict__ t6,
                                                   const __hip_bfloat16* __restrict__ t3,
                                                   float* __restrict__ P4) {
  __shared__ __align__(16) __hip_bfloat16 lA[64 * 64];
  __shared__ __align__(16) __hip_bfloat16 lB[64 * 64];
  int bx = blockIdx.x;
  int cbk = bx & 3, kc = bx >> 2;
  int db = blockIdx.y;
  int n = blockIdx.z;
  int t = threadIdx.x;
  int wave = t >> 6, lane = t & 63;
  int wm = wave >> 1, wn = wave & 1;
  int l16 = lane & 15, lg = lane >> 4;
  int d0 = db * 64;
  int c0 = cbk * 64;
  int kbase = kc * 1024;
  const __hip_bfloat16* An = t6 + (size_t)n * CD * SD + kbase;
  const __hip_bfloat16* Bn = t3 + (size_t)n * CD * SD + kbase;

  int srow = t >> 3;
  int scol = (t & 7) * 8;
  const __hip_bfloat16* gA0 = An + (size_t)(d0 + srow) * SD + scol;
  const __hip_bfloat16* gA1 = An + (size_t)(d0 + srow + 32) * SD + scol;
  const __hip_bfloat16* gB0 = Bn + (size_t)(c0 + srow) * SD + scol;
  const __hip_bfloat16* gB1 = Bn + (size_t)(c0 + srow + 32) * SD + scol;
  __hip_bfloat16* lAd0 = &lA[t * 8];
  __hip_bfloat16* lAd1 = &lA[t * 8 + 32 * 64];
  __hip_bfloat16* lBd0 = &lB[t * 8];
  __hip_bfloat16* lBd1 = &lB[t * 8 + 32 * 64];

  f32x4 acc[2][2];
#pragma unroll
  for (int mi = 0; mi < 2; ++mi)
#pragma unroll
    for (int ni = 0; ni < 2; ++ni) acc[mi][ni] = (f32x4){0.f, 0.f, 0.f, 0.f};

  gload16(gA0, lAd0);
  gload16(gA1, lAd1);
  gload16(gB0, lBd0);
  gload16(gB1, lBd1);

  for (int k = 0; k < 16; ++k) {
    __syncthreads();
#pragma unroll
    for (int ks = 0; ks < 2; ++ks) {
      bf16x8 a[2], b[2];
#pragma unroll
      for (int mi = 0; mi < 2; ++mi)
        a[mi] = *reinterpret_cast<const bf16x8*>(&lA[(wm * 32 + mi * 16 + l16) * 64 + ks * 32 + lg * 8]);
#pragma unroll
      for (int ni = 0; ni < 2; ++ni)
        b[ni] = *reinterpret_cast<const bf16x8*>(&lB[(wn * 32 + ni * 16 + l16) * 64 + ks * 32 + lg * 8]);
#pragma unroll
      for (int mi = 0; mi < 2; ++mi)
#pragma unroll
        for (int ni = 0; ni < 2; ++ni)
          acc[mi][ni] = __builtin_amdgcn_mfma_f32_16x16x32_bf16(a[mi], b[ni], acc[mi][ni], 0, 0, 0);
    }
    __syncthreads();
    if (k < 15) {
      int kk = (k + 1) * 64;
      gload16(gA0 + kk, lAd0);
      gload16(gA1 + kk, lAd1);
      gload16(gB0 + kk, lBd0);
      gload16(gB1 + kk, lBd1);
    }
  }

  float* Pn = P4 + ((size_t)kc * NB + n) * CD * CD;
#pragma unroll
  for (int mi = 0; mi < 2; ++mi)
#pragma unroll
    for (int ni = 0; ni < 2; ++ni) {
      int col = c0 + wn * 32 + ni * 16 + l16;
      int row0 = d0 + wm * 32 + mi * 16 + lg * 4;
#pragma unroll
      for (int r = 0; r < 4; ++r)
        Pn[(size_t)(row0 + r) * CD + col] = acc[mi][ni][r];
    }
}

// ---------------- reduce P4 -> P (bf16, x 1/64) ----------------
__global__ __launch_bounds__(256) void reduce_P(const float* __restrict__ P4,
                                                __hip_bfloat16* __restrict__ P) {
  size_t i = ((size_t)blockIdx.x * 256 + threadIdx.x) * 4;
  const size_t stride = (size_t)NB * CD * CD;
  float4 a = *reinterpret_cast<const float4*>(P4 + i);
  float4 b = *reinterpret_cast<const float4*>(P4 + stride + i);
  float4 c = *reinterpret_cast<const float4*>(P4 + 2 * stride + i);
  float4 d = *reinterpret_cast<const float4*>(P4 + 3 * stride + i);
  __hip_bfloat16 o[4];
  o[0] = __float2bfloat16((a.x + b.x + c.x + d.x) * 0.015625f);
  o[1] = __float2bfloat16((a.y + b.y + c.y + d.y) * 0.015625f);
  o[2] = __float2bfloat16((a.z + b.z + c.z + d.z) * 0.015625f);
  o[3] = __float2bfloat16((a.w + b.w + c.w + d.w) * 0.015625f);
  *reinterpret_cast<short4*>(&P[i]) = *reinterpret_cast<const short4*>(o);
}

// ---------------- GEMM D: out[n][d][s] = (1/16) * sum_c P[n][d][c] * t5T[n][s][c] -------
// tile 256(d, full)x128(s), BK=64, grid (32,1,16)=512 blocks = 2/CU.
#define DSTAGE_A(i, kk)                                                                \
  gload16(Pb + (size_t)((i) * 32 + wv4 * 8 + (lane >> 3)) * 512 + (kk) * 128 + cbsrc,  \
          (char*)lA + (i) * 4096 + wv4 * 1024)
#define DSTAGE_B(i, kk)                                                                \
  gload16(Tb + (size_t)(s0 + (i) * 32 + wv4 * 8 + (lane >> 3)) * 512 + (kk) * 128 + cbsrc, \
          (char*)lB + (i) * 4096 + wv4 * 1024)

__global__ __launch_bounds__(256, 2) void gemm_d(const __hip_bfloat16* __restrict__ P,
                                                 const __hip_bfloat16* __restrict__ t5T,
                                                 float* __restrict__ out) {
  __shared__ __align__(16) __hip_bfloat16 lA[256 * 64];  // 32 KB
  __shared__ __align__(16) __hip_bfloat16 lB[128 * 64];  // 16 KB
  const int n = blockIdx.z;
  const int sb = blockIdx.x;
  const int t = threadIdx.x;
  const int wv4 = t >> 6, lane = t & 63;
  const int wm = wv4 >> 1, wn = wv4 & 1;
  const int l16 = lane & 15, lg = lane >> 4;
  const int s0 = sb * 128;
  const char* Pb = (const char*)(P + (size_t)n * CD * CD);
  const char* Tb = (const char*)(t5T + (size_t)n * SD * CD);
  const int cbsrc = ((lane & 7) ^ (lane >> 3)) * 16;
  const int lxor = (l16 & 7) * 8;

  f32x4 acc[8][4];
#pragma unroll
  for (int i = 0; i < 8; ++i)
#pragma unroll
    for (int j = 0; j < 4; ++j) acc[i][j] = (f32x4){0.f, 0.f, 0.f, 0.f};

#pragma unroll
  for (int i = 0; i < 8; ++i) DSTAGE_A(i, 0);
#pragma unroll
  for (int i = 0; i < 4; ++i) DSTAGE_B(i, 0);

  for (int k = 0; k < 4; ++k) {
    __syncthreads();
#pragma unroll
    for (int ks = 0; ks < 2; ++ks) {
      int cb = (ks * 32 + lg * 8) ^ lxor;
      bf16x8 a[8], b[4];
#pragma unroll
      for (int mf = 0; mf < 8; ++mf)
        a[mf] = *reinterpret_cast<const bf16x8*>(&lA[(wm * 128 + mf * 16 + l16) * 64 + cb]);
#pragma unroll
      for (int nf = 0; nf < 4; ++nf)
        b[nf] = *reinterpret_cast<const bf16x8*>(&lB[(wn * 64 + nf * 16 + l16) * 64 + cb]);
#pragma unroll
      for (int mf = 0; mf < 8; ++mf)
#pragma unroll
        for (int nf = 0; nf < 4; ++nf)
          acc[mf][nf] = __builtin_amdgcn_mfma_f32_16x16x32_bf16(a[mf], b[nf], acc[mf][nf], 0, 0, 0);
    }
    __syncthreads();
    if (k < 3) {
      int kk = k + 1;
#pragma unroll
      for (int i = 0; i < 8; ++i) DSTAGE_A(i, kk);
#pragma unroll
      for (int i = 0; i < 4; ++i) DSTAGE_B(i, kk);
    }
  }

  float* outn = out + (size_t)n * CD * SD;
#pragma unroll
  for (int mf = 0; mf < 8; ++mf)
#pragma unroll
    for (int nf = 0; nf < 4; ++nf) {
      int col = s0 + wn * 64 + nf * 16 + l16;
      int row0 = wm * 128 + mf * 16 + lg * 4;
#pragma unroll
      for (int r = 0; r < 4; ++r)
        outn[(size_t)(row0 + r) * SD + col] = acc[mf][nf][r] * 0.0625f;
    }
}

extern "C" void kernel_launch(void* const* d_in, const int* in_sizes, int n_in,
                              void* d_out, int out_size, void* d_ws, size_t ws_size,
                              hipStream_t stream) {
  const float* x = (const float*)d_in[0];
  const float* p2 = (const float*)d_in[1];
  const float* p3 = (const float*)d_in[2];
  const float* p4 = (const float*)d_in[3];
  const float* p6 = (const float*)d_in[4];

  char* ws = (char*)d_ws;
  size_t off = 0;
  __hip_bfloat16* A = (__hip_bfloat16*)(ws + off);
  off += (size_t)CD * KU * 2;                       // 640 KiB
  size_t t2p_off = off;
  __hip_bfloat16* t2p = (__hip_bfloat16*)(ws + off);
  off += (size_t)NB * HD * WP * CD * 2;             // ~35.7 MiB
  __hip_bfloat16* t5T = (__hip_bfloat16*)(ws + off);
  off += (size_t)NB * SD * CD * 2;                  // 32 MiB
  __hip_bfloat16* t6 = (__hip_bfloat16*)(ws + off);
  off += (size_t)NB * CD * SD * 2;                  // 32 MiB
  __hip_bfloat16* t3 = (__hip_bfloat16*)(ws + off);
  off += (size_t)NB * CD * SD * 2;                  // 32 MiB
  float* P4 = (float*)(ws + t2p_off);
  __hip_bfloat16* P = (__hip_bfloat16*)(ws + t2p_off + (size_t)4 * NB * CD * CD * 4);

  float* out = (float*)d_out;

  prep_w3<<<dim3((CD * KU + 255) / 256), 256, 0, stream>>>(p3, A);
  prep_x<<<dim3(HD, 4, NB), 256, 0, stream>>>(x, p2, p4, p6, t2p, t5T, t6);
  gemm_b8<<<dim3(16, 1, NB), 512, 0, stream>>>(A, t2p, t3);
  gemm_c_part<<<dim3(16, 4, NB), 256, 0, stream>>>(t6, t3, P4);
  reduce_P<<<dim3((NB * CD * CD / 4) / 256), 256, 0, stream>>>(P4, P);
  gemm_d<<<dim3(32, 1, NB), 256, 0, stream>>>(P, t5T, out);
}

// Round 10
// 129.130 us; speedup vs baseline: 1.0321x; 1.0321x over previous
//
#include <hip/hip_runtime.h>
#include <hip/hip_bf16.h>

typedef __attribute__((ext_vector_type(8))) short bf16x8;
typedef __attribute__((ext_vector_type(4))) float f32x4;

#define NB 16
#define CD 256
#define HD 64
#define WD 64
#define WP 68   // padded width
#define SD 4096
#define KU 1280  // 5 * 256

__device__ __forceinline__ void gload16(const void* g, void* lds) {
  __builtin_amdgcn_global_load_lds(
      (const __attribute__((address_space(1))) unsigned int*)g,
      (__attribute__((address_space(3))) unsigned int*)lds, 16, 0, 0);
}

// ---------------- prep X (+ merged prep_w3): t2p, t5T, t6, A ----------------
__global__ __launch_bounds__(256) void prep_x(const float* __restrict__ x,
                                              const float* __restrict__ p2,
                                              const float* __restrict__ p4,
                                              const float* __restrict__ p6,
                                              const float* __restrict__ p3,
                                              __hip_bfloat16* __restrict__ t2p,
                                              __hip_bfloat16* __restrict__ t5T,
                                              __hip_bfloat16* __restrict__ t6,
                                              __hip_bfloat16* __restrict__ A) {
  int h = blockIdx.x;
  int c0 = blockIdx.y * 64;
  int n = blockIdx.z;
  __shared__ float xl[64][67];
  __shared__ float p2l[64];
  __shared__ float wtl[64][8];
  int t = threadIdx.x;

  // merged prep_w3: A[o][j*256+c] = p3[o,c,0,j]
  {
    int bid = (n * 64 + h) * 4 + blockIdx.y;  // 0..4095
    int id = bid * 256 + t;
    if (id < CD * KU) {
      int o = id / KU;
      int r = id - o * KU;
      int j = r >> 8;
      int c = r & 255;
      A[id] = __float2bfloat16(p3[(o * CD + c) * 5 + j]);
    }
  }

  if (t < 64) p2l[t] = p2[(c0 + t) * HD + h];
  for (int idx = t; idx < 448; idx += 256) {
    int c = idx / 7, k = idx - c * 7;
    wtl[c][k] = p4[(c0 + c) * 7 + k] * p6[k];
  }

  {
    int cq = t >> 4;
    int w4 = (t & 15) * 4;
#pragma unroll
    for (int cc = 0; cc < 4; ++cc) {
      int cl = cc * 16 + cq;
      const float4 xv = *reinterpret_cast<const float4*>(
          &x[(((size_t)n * CD + c0 + cl) * HD + h) * WD + w4]);
      xl[cl][w4 + 0] = xv.x;
      xl[cl][w4 + 1] = xv.y;
      xl[cl][w4 + 2] = xv.z;
      xl[cl][w4 + 3] = xv.w;
    }
  }
  __syncthreads();

  __hip_bfloat16* t2pn = t2p + (size_t)n * HD * WP * CD;
#pragma unroll
  for (int ii = 0; ii < 2; ++ii) {
    int w = (t >> 3) + ii * 32;
    int cb = (t & 7) * 8;
    __hip_bfloat16 o2[8], o5[8];
#pragma unroll
    for (int j = 0; j < 8; ++j) {
      float xv = xl[cb + j][w];
      o5[j] = __float2bfloat16(fmaxf(xv, 0.f));
      o2[j] = __float2bfloat16(p2l[cb + j] * xv);
    }
    size_t s = (size_t)h * 64 + w;
    *reinterpret_cast<bf16x8*>(&t5T[((size_t)n * SD + s) * CD + c0 + cb]) =
        *reinterpret_cast<const bf16x8*>(o5);
    *reinterpret_cast<bf16x8*>(&t2pn[((size_t)h * WP + w + 2) * CD + c0 + cb]) =
        *reinterpret_cast<const bf16x8*>(o2);
  }
  if (t < 32) {
    int pi = t >> 3;
    int wp = (pi < 2) ? pi : pi + 64;
    int cb = (t & 7) * 8;
    bf16x8 z = (bf16x8){0, 0, 0, 0, 0, 0, 0, 0};
    *reinterpret_cast<bf16x8*>(&t2pn[((size_t)h * WP + wp) * CD + c0 + cb]) = z;
  }

#pragma unroll
  for (int ii = 0; ii < 2; ++ii) {
    int cl = (t >> 3) + ii * 32;
    int w8 = (t & 7) * 8;
    float hx[14];
#pragma unroll
    for (int m = 0; m < 14; ++m) {
      int wi = w8 - 3 + m;
      hx[m] = (wi >= 0 && wi < 64) ? xl[cl][wi] : 0.f;
    }
    float wt[7];
#pragma unroll
    for (int k = 0; k < 7; ++k) wt[k] = wtl[cl][k];
    __hip_bfloat16 o6[8];
#pragma unroll
    for (int u = 0; u < 8; ++u) {
      float acc = 0.f;
#pragma unroll
      for (int k = 0; k < 7; ++k) acc += wt[k] * hx[u + k];
      o6[u] = __float2bfloat16(acc);
    }
    *reinterpret_cast<bf16x8*>(&t6[((size_t)n * CD + c0 + cl) * SD + h * 64 + w8]) =
        *reinterpret_cast<const bf16x8*>(o6);
  }
}

// ---------------- GEMM B (depth-2 pipeline, 256x256 tile, BK=32, 4 LDS bufs) -----------
// grid: (sb=16, 1, n=16) = 256 blocks, 512 threads (8 waves 2Mx4N, wave tile 128x64)
// LDS: 4 bufs x (A 256x32 + B 256x32) bf16 = 4 x 32KB = 128 KiB.
// Per tile: 4 gload16/thread; VMWAIT(4) counted (never 0 in steady state) — 2-tile slack.
// Fragments register-double-buffered (X/Y): MFMA phase is pure-register; ds_reads of
// tile k+1 overlap MFMAs of tile k. 1 barrier/tile.
// Swizzle (64B rows): phys granule = lg ^ ((row>>1)&3); source granule (t&3)^((t>>3)&3).
#define VMWAIT(N) asm volatile("s_waitcnt vmcnt(" #N ")" ::: "memory")
#define BARRIER() __builtin_amdgcn_s_barrier()

#define ST4(kt, bi)                                                                    \
  do {                                                                                 \
    char* dst = lb + ((bi) << 15) + t * 16;                                            \
    gload16(gA0 + (kt) * 64, dst);                                                     \
    gload16(gA1 + (kt) * 64, dst + 8192);                                              \
    gload16(gB0 + (kt) * 64, dst + 16384);                                             \
    gload16(gB1 + (kt) * 64, dst + 24576);                                             \
  } while (0)

#define LDF(bi, AV, BV)                                                                \
  do {                                                                                 \
    const char* ba = lb + ((bi) << 15);                                                \
    _Pragma("unroll") for (int mf = 0; mf < 8; ++mf) {                                 \
      int row = wm * 128 + mf * 16 + l16;                                              \
      AV[mf] = *reinterpret_cast<const bf16x8*>(ba + row * 64 + ((lg ^ rxor) * 16));   \
    }                                                                                  \
    _Pragma("unroll") for (int nf = 0; nf < 4; ++nf) {                                 \
      int row = wn * 64 + nf * 16 + l16;                                               \
      BV[nf] = *reinterpret_cast<const bf16x8*>(ba + 16384 + row * 64 +                \
                                                ((lg ^ rxor) * 16));                   \
    }                                                                                  \
  } while (0)

#define MM(AV, BV)                                                                     \
  do {                                                                                 \
    __builtin_amdgcn_s_setprio(1);                                                     \
    _Pragma("unroll") for (int mf = 0; mf < 8; ++mf)                                   \
        _Pragma("unroll") for (int nf = 0; nf < 4; ++nf)                               \
            acc[mf][nf] = __builtin_amdgcn_mfma_f32_16x16x32_bf16(AV[mf], BV[nf],      \
                                                                  acc[mf][nf], 0, 0, 0); \
    __builtin_amdgcn_s_setprio(0);                                                     \
  } while (0)

__global__ __launch_bounds__(512, 2) void gemm_b8(const __hip_bfloat16* __restrict__ A,
                                                  const __hip_bfloat16* __restrict__ t2p,
                                                  __hip_bfloat16* __restrict__ t3) {
  __shared__ __align__(16) __hip_bfloat16 lds[65536];  // 128 KiB = 4 x 32 KB
  char* lb = (char*)lds;
  const int n = blockIdx.z;
  const int sb = blockIdx.x;
  const int t = threadIdx.x;
  const int wv = t >> 6, lane = t & 63;
  const int wm = wv >> 2, wn = wv & 3;
  const int l16 = lane & 15, lg = lane >> 4;
  const int s0 = sb * 256;
  const int rxor = (l16 >> 1) & 3;
  const char* Ab = (const char*)A;
  const char* t2pb = (const char*)(t2p + (size_t)n * HD * WP * CD);
  const int cbsrc = ((t & 3) ^ ((t >> 3) & 3)) * 16;  // src-side granule swizzle

  // per-thread staging bases (row = t>>2 and +128)
  const int r0 = t >> 2;
  const char* gA0 = Ab + (size_t)r0 * 2560 + cbsrc;
  const char* gA1 = Ab + (size_t)(r0 + 128) * 2560 + cbsrc;
  const int s1 = s0 + r0, s2 = s0 + r0 + 128;
  const char* gB0 = t2pb + (size_t)(s1 + 4 * (s1 >> 6)) * 512 + cbsrc;
  const char* gB1 = t2pb + (size_t)(s2 + 4 * (s2 >> 6)) * 512 + cbsrc;

  f32x4 acc[8][4];
#pragma unroll
  for (int i = 0; i < 8; ++i)
#pragma unroll
    for (int j = 0; j < 4; ++j) acc[i][j] = (f32x4){0.f, 0.f, 0.f, 0.f};

  bf16x8 avX[8], bvX[4], avY[8], bvY[4];

  // prologue: tiles 0,1 staged; validate tile 0; preload its fragments
  ST4(0, 0);
  ST4(1, 1);
  VMWAIT(4);
  BARRIER();
  LDF(0, avX, bvX);

  // main loop: tiles 0..35 (2 per iteration)
  for (int k2 = 0; k2 < 18; ++k2) {
    const int kt = k2 * 2;
    ST4(kt + 2, (kt + 2) & 3);
    MM(avX, bvX);                       // tile kt (pure-register)
    VMWAIT(4);                          // tile kt+1 complete (kt+2 still in flight)
    BARRIER();
    LDF((kt + 1) & 3, avY, bvY);
    ST4(kt + 3, (kt + 3) & 3);
    MM(avY, bvY);                       // tile kt+1
    VMWAIT(4);                          // tile kt+2 complete
    BARRIER();
    LDF((kt + 2) & 3, avX, bvX);
  }
  // peel tiles 36..39 (X holds 36)
  ST4(38, 2);
  MM(avX, bvX);                         // t36
  VMWAIT(4);
  BARRIER();
  LDF(1, avY, bvY);                     // t37
  ST4(39, 3);
  MM(avY, bvY);                         // t37
  VMWAIT(4);
  BARRIER();
  LDF(2, avX, bvX);                     // t38
  MM(avX, bvX);                         // t38
  VMWAIT(0);
  BARRIER();
  LDF(3, avY, bvY);                     // t39
  MM(avY, bvY);                         // t39

  __hip_bfloat16* t3n = t3 + (size_t)n * CD * SD;
#pragma unroll
  for (int im = 0; im < 8; ++im)
#pragma unroll
    for (int in = 0; in < 4; ++in) {
      int row0 = wm * 128 + im * 16 + lg * 4;
      int col = s0 + wn * 64 + in * 16 + l16;
#pragma unroll
      for (int r = 0; r < 4; ++r)
        t3n[(size_t)(row0 + r) * SD + col] = __float2bfloat16(acc[im][in][r]);
    }
}

// ---------------- GEMM C (K-split x4): P4[kc][n][d][c] = sum_{s in chunk} t6*t3 ---------
__global__ __launch_bounds__(256) void gemm_c_part(const __hip_bfloat16* __restrict__ t6,
                                                   const __hip_bfloat16* __restrict__ t3,
                                                   float* __restrict__ P4) {
  __shared__ __align__(16) __hip_bfloat16 lA[64 * 64];
  __shared__ __align__(16) __hip_bfloat16 lB[64 * 64];
  int bx = blockIdx.x;
  int cbk = bx & 3, kc = bx >> 2;
  int db = blockIdx.y;
  int n = blockIdx.z;
  int t = threadIdx.x;
  int wave = t >> 6, lane = t & 63;
  int wm = wave >> 1, wn = wave & 1;
  int l16 = lane & 15, lg = lane >> 4;
  int d0 = db * 64;
  int c0 = cbk * 64;
  int kbase = kc * 1024;
  const __hip_bfloat16* An = t6 + (size_t)n * CD * SD + kbase;
  const __hip_bfloat16* Bn = t3 + (size_t)n * CD * SD + kbase;

  int srow = t >> 3;
  int scol = (t & 7) * 8;
  const __hip_bfloat16* gA0 = An + (size_t)(d0 + srow) * SD + scol;
  const __hip_bfloat16* gA1 = An + (size_t)(d0 + srow + 32) * SD + scol;
  const __hip_bfloat16* gB0 = Bn + (size_t)(c0 + srow) * SD + scol;
  const __hip_bfloat16* gB1 = Bn + (size_t)(c0 + srow + 32) * SD + scol;
  __hip_bfloat16* lAd0 = &lA[t * 8];
  __hip_bfloat16* lAd1 = &lA[t * 8 + 32 * 64];
  __hip_bfloat16* lBd0 = &lB[t * 8];
  __hip_bfloat16* lBd1 = &lB[t * 8 + 32 * 64];

  f32x4 acc[2][2];
#pragma unroll
  for (int mi = 0; mi < 2; ++mi)
#pragma unroll
    for (int ni = 0; ni < 2; ++ni) acc[mi][ni] = (f32x4){0.f, 0.f, 0.f, 0.f};

  gload16(gA0, lAd0);
  gload16(gA1, lAd1);
  gload16(gB0, lBd0);
  gload16(gB1, lBd1);

  for (int k = 0; k < 16; ++k) {
    __syncthreads();
#pragma unroll
    for (int ks = 0; ks < 2; ++ks) {
      bf16x8 a[2], b[2];
#pragma unroll
      for (int mi = 0; mi < 2; ++mi)
        a[mi] = *reinterpret_cast<const bf16x8*>(&lA[(wm * 32 + mi * 16 + l16) * 64 + ks * 32 + lg * 8]);
#pragma unroll
      for (int ni = 0; ni < 2; ++ni)
        b[ni] = *reinterpret_cast<const bf16x8*>(&lB[(wn * 32 + ni * 16 + l16) * 64 + ks * 32 + lg * 8]);
#pragma unroll
      for (int mi = 0; mi < 2; ++mi)
#pragma unroll
        for (int ni = 0; ni < 2; ++ni)
          acc[mi][ni] = __builtin_amdgcn_mfma_f32_16x16x32_bf16(a[mi], b[ni], acc[mi][ni], 0, 0, 0);
    }
    __syncthreads();
    if (k < 15) {
      int kk = (k + 1) * 64;
      gload16(gA0 + kk, lAd0);
      gload16(gA1 + kk, lAd1);
      gload16(gB0 + kk, lBd0);
      gload16(gB1 + kk, lBd1);
    }
  }

  float* Pn = P4 + ((size_t)kc * NB + n) * CD * CD;
#pragma unroll
  for (int mi = 0; mi < 2; ++mi)
#pragma unroll
    for (int ni = 0; ni < 2; ++ni) {
      int col = c0 + wn * 32 + ni * 16 + l16;
      int row0 = d0 + wm * 32 + mi * 16 + lg * 4;
#pragma unroll
      for (int r = 0; r < 4; ++r)
        Pn[(size_t)(row0 + r) * CD + col] = acc[mi][ni][r];
    }
}

// ---------------- reduce P4 -> P (bf16, x 1/64) ----------------
__global__ __launch_bounds__(256) void reduce_P(const float* __restrict__ P4,
                                                __hip_bfloat16* __restrict__ P) {
  size_t i = ((size_t)blockIdx.x * 256 + threadIdx.x) * 4;
  const size_t stride = (size_t)NB * CD * CD;
  float4 a = *reinterpret_cast<const float4*>(P4 + i);
  float4 b = *reinterpret_cast<const float4*>(P4 + stride + i);
  float4 c = *reinterpret_cast<const float4*>(P4 + 2 * stride + i);
  float4 d = *reinterpret_cast<const float4*>(P4 + 3 * stride + i);
  __hip_bfloat16 o[4];
  o[0] = __float2bfloat16((a.x + b.x + c.x + d.x) * 0.015625f);
  o[1] = __float2bfloat16((a.y + b.y + c.y + d.y) * 0.015625f);
  o[2] = __float2bfloat16((a.z + b.z + c.z + d.z) * 0.015625f);
  o[3] = __float2bfloat16((a.w + b.w + c.w + d.w) * 0.015625f);
  *reinterpret_cast<short4*>(&P[i]) = *reinterpret_cast<const short4*>(o);
}

// ---------------- GEMM D: out[n][d][s] = (1/16) * sum_c P[n][d][c] * t5T[n][s][c] -------
#define DSTAGE_A(i, kk)                                                                \
  gload16(Pb + (size_t)((i) * 32 + wv4 * 8 + (lane >> 3)) * 512 + (kk) * 128 + cbsrc,  \
          (char*)lA + (i) * 4096 + wv4 * 1024)
#define DSTAGE_B(i, kk)                                                                \
  gload16(Tb + (size_t)(s0 + (i) * 32 + wv4 * 8 + (lane >> 3)) * 512 + (kk) * 128 + cbsrc, \
          (char*)lB + (i) * 4096 + wv4 * 1024)

__global__ __launch_bounds__(256, 2) void gemm_d(const __hip_bfloat16* __restrict__ P,
                                                 const __hip_bfloat16* __restrict__ t5T,
                                                 float* __restrict__ out) {
  __shared__ __align__(16) __hip_bfloat16 lA[256 * 64];  // 32 KB
  __shared__ __align__(16) __hip_bfloat16 lB[128 * 64];  // 16 KB
  const int n = blockIdx.z;
  const int sb = blockIdx.x;
  const int t = threadIdx.x;
  const int wv4 = t >> 6, lane = t & 63;
  const int wm = wv4 >> 1, wn = wv4 & 1;
  const int l16 = lane & 15, lg = lane >> 4;
  const int s0 = sb * 128;
  const char* Pb = (const char*)(P + (size_t)n * CD * CD);
  const char* Tb = (const char*)(t5T + (size_t)n * SD * CD);
  const int cbsrc = ((lane & 7) ^ (lane >> 3)) * 16;
  const int lxor = (l16 & 7) * 8;

  f32x4 acc[8][4];
#pragma unroll
  for (int i = 0; i < 8; ++i)
#pragma unroll
    for (int j = 0; j < 4; ++j) acc[i][j] = (f32x4){0.f, 0.f, 0.f, 0.f};

#pragma unroll
  for (int i = 0; i < 8; ++i) DSTAGE_A(i, 0);
#pragma unroll
  for (int i = 0; i < 4; ++i) DSTAGE_B(i, 0);

  for (int k = 0; k < 4; ++k) {
    __syncthreads();
#pragma unroll
    for (int ks = 0; ks < 2; ++ks) {
      int cb = (ks * 32 + lg * 8) ^ lxor;
      bf16x8 a[8], b[4];
#pragma unroll
      for (int mf = 0; mf < 8; ++mf)
        a[mf] = *reinterpret_cast<const bf16x8*>(&lA[(wm * 128 + mf * 16 + l16) * 64 + cb]);
#pragma unroll
      for (int nf = 0; nf < 4; ++nf)
        b[nf] = *reinterpret_cast<const bf16x8*>(&lB[(wn * 64 + nf * 16 + l16) * 64 + cb]);
#pragma unroll
      for (int mf = 0; mf < 8; ++mf)
#pragma unroll
        for (int nf = 0; nf < 4; ++nf)
          acc[mf][nf] = __builtin_amdgcn_mfma_f32_16x16x32_bf16(a[mf], b[nf], acc[mf][nf], 0, 0, 0);
    }
    __syncthreads();
    if (k < 3) {
      int kk = k + 1;
#pragma unroll
      for (int i = 0; i < 8; ++i) DSTAGE_A(i, kk);
#pragma unroll
      for (int i = 0; i < 4; ++i) DSTAGE_B(i, kk);
    }
  }

  float* outn = out + (size_t)n * CD * SD;
#pragma unroll
  for (int mf = 0; mf < 8; ++mf)
#pragma unroll
    for (int nf = 0; nf < 4; ++nf) {
      int col = s0 + wn * 64 + nf * 16 + l16;
      int row0 = wm * 128 + mf * 16 + lg * 4;
#pragma unroll
      for (int r = 0; r < 4; ++r)
        outn[(size_t)(row0 + r) * SD + col] = acc[mf][nf][r] * 0.0625f;
    }
}

extern "C" void kernel_launch(void* const* d_in, const int* in_sizes, int n_in,
                              void* d_out, int out_size, void* d_ws, size_t ws_size,
                              hipStream_t stream) {
  const float* x = (const float*)d_in[0];
  const float* p2 = (const float*)d_in[1];
  const float* p3 = (const float*)d_in[2];
  const float* p4 = (const float*)d_in[3];
  const float* p6 = (const float*)d_in[4];

  char* ws = (char*)d_ws;
  size_t off = 0;
  __hip_bfloat16* A = (__hip_bfloat16*)(ws + off);
  off += (size_t)CD * KU * 2;                       // 640 KiB
  size_t t2p_off = off;
  __hip_bfloat16* t2p = (__hip_bfloat16*)(ws + off);
  off += (size_t)NB * HD * WP * CD * 2;             // ~35.7 MiB
  __hip_bfloat16* t5T = (__hip_bfloat16*)(ws + off);
  off += (size_t)NB * SD * CD * 2;                  // 32 MiB
  __hip_bfloat16* t6 = (__hip_bfloat16*)(ws + off);
  off += (size_t)NB * CD * SD * 2;                  // 32 MiB
  __hip_bfloat16* t3 = (__hip_bfloat16*)(ws + off);
  off += (size_t)NB * CD * SD * 2;                  // 32 MiB
  float* P4 = (float*)(ws + t2p_off);
  __hip_bfloat16* P = (__hip_bfloat16*)(ws + t2p_off + (size_t)4 * NB * CD * CD * 4);

  float* out = (float*)d_out;

  prep_x<<<dim3(HD, 4, NB), 256, 0, stream>>>(x, p2, p4, p6, p3, t2p, t5T, t6, A);
  gemm_b8<<<dim3(16, 1, NB), 512, 0, stream>>>(A, t2p, t3);
  gemm_c_part<<<dim3(16, 4, NB), 256, 0, stream>>>(t6, t3, P4);
  reduce_P<<<dim3((NB * CD * CD / 4) / 256), 256, 0, stream>>>(P4, P);
  gemm_d<<<dim3(32, 1, NB), 256, 0, stream>>>(P, t5T, out);
}